// Round 1
// baseline (191.488 us; speedup 1.0000x reference)
//
#include <hip/hip_runtime.h>
#include <math.h>

#define IMG_H 512
#define IMG_W 512
#define NPLANES 48            // 16 * 3
#define RAD 5
#define TAPS 11
#define CHUNK 66              // 6 * TAPS, so ring phase is static after unroll-by-11
#define TILE_X 256
#define ROWBUF 272            // 266 used, padded

struct GaussW { float w[TAPS]; };

__global__ __launch_bounds__(256, 4)
void ssim_main(const float* __restrict__ img1, const float* __restrict__ img2,
               double* __restrict__ sum_ws, GaussW gw) {
    __shared__ float2 srow[2][ROWBUF];   // (x1, x2) interleaved row, double-buffered
    __shared__ float wsum[4];

    const int tid = threadIdx.x;
    const int cx0 = blockIdx.x * TILE_X;
    const int y0  = blockIdx.y * CHUNK;
    const size_t pbase = (size_t)blockIdx.z * (IMG_H * IMG_W);
    const float* p1 = img1 + pbase;
    const float* p2 = img2 + pbase;

    // register ring: horizontal conv results for the 5 quantities, 11 rows deep
    float r1[TAPS], r2[TAPS], r11[TAPS], r22[TAPS], r12[TAPS];

    auto stage = [&](int r, int p) {
        if (r >= 0 && r < IMG_H) {
            const float* row1 = p1 + (size_t)r * IMG_W;
            const float* row2 = p2 + (size_t)r * IMG_W;
            int col = cx0 - RAD + tid;
            float a = 0.f, b = 0.f;
            if (col >= 0 && col < IMG_W) { a = row1[col]; b = row2[col]; }
            srow[p][tid] = make_float2(a, b);
            if (tid < TILE_X + 2 * RAD - 256) {   // tid < 10: tail columns 256..265
                int i = 256 + tid;
                int c2 = cx0 - RAD + i;
                float a2 = 0.f, b2 = 0.f;
                if (c2 >= 0 && c2 < IMG_W) { a2 = row1[c2]; b2 = row2[c2]; }
                srow[p][i] = make_float2(a2, b2);
            }
        }
    };

    auto hconv = [&](int r, int p, float& o1, float& o2, float& o11, float& o22, float& o12) {
        float a1 = 0.f, a2 = 0.f, a11 = 0.f, a22 = 0.f, a12 = 0.f;
        if (r >= 0 && r < IMG_H) {   // zero-padded rows contribute zero
            #pragma unroll
            for (int d = 0; d < TAPS; ++d) {
                float2 v = srow[p][tid + d];
                float wv = gw.w[d];
                a1  = fmaf(wv, v.x, a1);
                a2  = fmaf(wv, v.y, a2);
                a11 = fmaf(wv, v.x * v.x, a11);
                a22 = fmaf(wv, v.y * v.y, a22);
                a12 = fmaf(wv, v.x * v.y, a12);
            }
        }
        o1 = a1; o2 = a2; o11 = a11; o22 = a22; o12 = a12;
    };

    // prologue: local h-rows 0..9  (global rows y0-5 .. y0+4) -> slots 0..9
    #pragma unroll
    for (int k = 0; k < TAPS - 1; ++k) {
        int r = y0 - RAD + k;
        stage(r, k & 1);
        __syncthreads();
        hconv(r, k & 1, r1[k], r2[k], r11[k], r22[k], r12[k]);
    }

    const float C1v = 0.0001f;  // 0.01^2
    const float C2v = 0.0009f;  // 0.03^2
    float acc = 0.f;

    // main: 66 output rows, unrolled by 11 so all ring indices are static
    for (int kk = 0; kk < CHUNK; kk += TAPS) {
        #pragma unroll
        for (int j = 0; j < TAPS; ++j) {
            const int lr = (TAPS - 1) + kk + j;   // local h-row
            const int r  = y0 - RAD + lr;         // global input row
            const int p  = lr & 1;
            stage(r, p);
            __syncthreads();
            // new h-row into slot (10+j)%11 (static)
            hconv(r, p, r1[(j + 10) % TAPS], r2[(j + 10) % TAPS],
                  r11[(j + 10) % TAPS], r22[(j + 10) % TAPS], r12[(j + 10) % TAPS]);

            const int y = y0 + kk + j;            // output row
            if (y < IMG_H) {
                float mu1 = 0.f, mu2 = 0.f, s11 = 0.f, s22 = 0.f, s12 = 0.f;
                #pragma unroll
                for (int t = 0; t < TAPS; ++t) {
                    const int s = (j + t) % TAPS; // static after unroll
                    float wv = gw.w[t];
                    mu1 = fmaf(wv, r1[s], mu1);
                    mu2 = fmaf(wv, r2[s], mu2);
                    s11 = fmaf(wv, r11[s], s11);
                    s22 = fmaf(wv, r22[s], s22);
                    s12 = fmaf(wv, r12[s], s12);
                }
                float mu1sq = mu1 * mu1, mu2sq = mu2 * mu2, mu12 = mu1 * mu2;
                float sg1 = s11 - mu1sq, sg2 = s22 - mu2sq, sg12 = s12 - mu12;
                float num = (2.f * mu12 + C1v) * (2.f * sg12 + C2v);
                float den = (mu1sq + mu2sq + C1v) * (sg1 + sg2 + C2v);
                acc += num * __builtin_amdgcn_rcpf(den);
            }
        }
    }

    // wave (64-lane) shuffle reduce, then block partials, then one atomic
    #pragma unroll
    for (int off = 32; off > 0; off >>= 1) acc += __shfl_down(acc, off, 64);
    if ((tid & 63) == 0) wsum[tid >> 6] = acc;
    __syncthreads();
    if (tid == 0) {
        double s = (double)wsum[0] + (double)wsum[1] + (double)wsum[2] + (double)wsum[3];
        atomicAdd(sum_ws, s);
    }
}

__global__ void ssim_finalize(const double* __restrict__ sum_ws, float* __restrict__ out) {
    out[0] = (float)(sum_ws[0] * (1.0 / (double)(16.0 * 3.0 * 512.0 * 512.0)));
}

extern "C" void kernel_launch(void* const* d_in, const int* in_sizes, int n_in,
                              void* d_out, int out_size, void* d_ws, size_t ws_size,
                              hipStream_t stream) {
    const float* img1 = (const float*)d_in[0];
    const float* img2 = (const float*)d_in[1];
    float* out = (float*)d_out;
    double* ws = (double*)d_ws;

    // d_ws is poisoned 0xAA before every launch — zero the accumulator (async, capture-safe)
    hipMemsetAsync(ws, 0, sizeof(double), stream);

    // Gaussian weights computed on host in double, passed via kernarg (SGPRs)
    GaussW gw;
    double g[TAPS], s = 0.0;
    for (int i = 0; i < TAPS; ++i) {
        double x = (double)(i - TAPS / 2);
        g[i] = exp(-(x * x) / (2.0 * 1.5 * 1.5));
        s += g[i];
    }
    for (int i = 0; i < TAPS; ++i) gw.w[i] = (float)(g[i] / s);

    dim3 grid(IMG_W / TILE_X, (IMG_H + CHUNK - 1) / CHUNK, NPLANES);  // 2 x 8 x 48 = 768 blocks
    ssim_main<<<grid, 256, 0, stream>>>(img1, img2, ws, gw);
    ssim_finalize<<<1, 1, 0, stream>>>(ws, out);
}